// Round 1
// 457.075 us; speedup vs baseline: 1.0885x; 1.0885x over previous
//
#include <hip/hip_runtime.h>

// Problem constants (B=4, S=4096, D=1024, BASE_K=256, MAX_K=512)
#define SDIM 4096
#define DDIM 1024
#define NROWS 16384
#define KOUT 512
#define CAP 1024   // candidate-compaction buffer slots per wave (>= KOUT, pow2)

__device__ __forceinline__ unsigned f2key(float f) {
    unsigned u = __float_as_uint(f);
    // monotonic bijection: larger key <=> larger float
    return (u & 0x80000000u) ? ~u : (u | 0x80000000u);
}
__device__ __forceinline__ float key2f(unsigned k) {
    unsigned u = (k & 0x80000000u) ? (k ^ 0x80000000u) : ~k;
    return __uint_as_float(u);
}
// popcount of mask restricted to lanes below mine
__device__ __forceinline__ unsigned lt_popc(unsigned long long m) {
    return __builtin_amdgcn_mbcnt_hi((unsigned)(m >> 32),
           __builtin_amdgcn_mbcnt_lo((unsigned)(m & 0xFFFFFFFFull), 0u));
}
// Per-wave LDS ordering: drain this wave's outstanding DS ops.
// Replaces __syncthreads(): every LDS region is a wave-private slice, so
// block-wide coupling of the 4 (imbalanced) waves is pure stall.
__device__ __forceinline__ void wave_lds_fence() {
    asm volatile("s_waitcnt lgkmcnt(0)" ::: "memory");
}

// One WAVE per row (4 rows per 256-thread block).
// __launch_bounds__(256, 1): VGPR cap 512 so key[64] stays RESIDENT in
// registers (default cap of 80 would spill it to scratch -> latency-bound).
__global__ __launch_bounds__(256, 1) void fused_kernel(
    const float* __restrict__ scores, const float* __restrict__ Q,
    const float* __restrict__ W, const float* __restrict__ bias,
    float* __restrict__ out_topk, float* __restrict__ out_k) {

    __shared__ unsigned sel[4][KOUT];   // 8 KB: final >T survivors per wave
    __shared__ unsigned cbuf[4][CAP];   // 16 KB: compacted candidates per wave

    const int tid  = threadIdx.x;
    const int lane = tid & 63;
    const int wid  = tid >> 6;
    const int row  = blockIdx.x * 4 + wid;

    // ---------------- gate ----------------
    {
        const float4* q4 = (const float4*)(Q + (size_t)row * DDIM);
        const float4* w4 = (const float4*)W;
        float g = 0.f;
#pragma unroll
        for (int i = 0; i < 4; ++i) {
            float4 a = q4[lane + 64 * i];
            float4 b = w4[lane + 64 * i];
            g += a.x * b.x + a.y * b.y + a.z * b.z + a.w * b.w;
        }
#pragma unroll
        for (int off = 32; off; off >>= 1) g += __shfl_down(g, off, 64);
        if (lane == 0) {
            float x   = g + bias[0];
            float imp = 1.0f / (1.0f + expf(-x));
            out_k[row] = (float)(int)(256.0f + 256.0f * imp);
        }
    }

    // ---------------- load 64 keys/lane into registers ----------------
    unsigned key[64];
    {
        const float4* src = (const float4*)(scores + (size_t)row * SDIM);
#pragma unroll
        for (int i = 0; i < 16; ++i) {
            float4 v = src[lane + 64 * i];
            key[4 * i + 0] = f2key(v.x);
            key[4 * i + 1] = f2key(v.y);
            key[4 * i + 2] = f2key(v.z);
            key[4 * i + 3] = f2key(v.w);
        }
    }

    // ---------------- threshold, phase A: wide bit search ------------------
    // invariant: cnt = count(key >= prefix) >= 512 at all times.
    // Break as soon as the candidate set fits CAP (incl. the exact-512 case);
    // the remaining mantissa bits are then resolved on 16 regs/lane instead
    // of 64 (quickselect-style set shrinking). For N(0,1) rows this loop runs
    // ~9 iterations (sign + exponent bits down to x>=1.0, cnt ~650).
    unsigned prefix = 0;
    unsigned cnt    = 4096;
    int      bnext  = -1;
    bool     trig   = false;
#pragma unroll 1
    for (int b = 31; b >= 0; --b) {
        const unsigned candk = prefix | (1u << b);
        unsigned total = 0;
#pragma unroll
        for (int i = 0; i < 64; ++i)
            total += (unsigned)__popcll(__ballot(key[i] >= candk));
        if (total >= (unsigned)KOUT) {   // wave-uniform
            prefix = candk;
            cnt    = total;
            if (cnt <= (unsigned)CAP) { bnext = b - 1; trig = true; break; }
        }
    }

    unsigned T;
    unsigned mtot = 0;

    if (trig) {
        // ---- compact candidates (key >= prefix, 512 < n <= 1024) to LDS ----
        {
            unsigned c = 0;
#pragma unroll
            for (int i = 0; i < 64; ++i) {
                bool p = key[i] >= prefix;
                unsigned long long m = __ballot(p);
                if (p) cbuf[wid][c + lt_popc(m)] = key[i];
                c += (unsigned)__popcll(m);
            }
        }
        wave_lds_fence();

        // 16 candidates/lane; tail slots masked to 0 (0 can never be >= any
        // candk since candk = prefix|bit > 0, and never > T).
        unsigned ck[16];
#pragma unroll
        for (int j = 0; j < 16; ++j) {
            unsigned idx = (unsigned)lane + 64u * (unsigned)j;
            unsigned v = cbuf[wid][idx];
            ck[j] = (idx < cnt) ? v : 0u;
        }

        // ---------------- threshold, phase B: narrow bit search -------------
        if (cnt > (unsigned)KOUT) {
#pragma unroll 1
            for (int b = bnext; b >= 0; --b) {
                const unsigned candk = prefix | (1u << b);
                unsigned total = 0;
#pragma unroll
                for (int j = 0; j < 16; ++j)
                    total += (unsigned)__popcll(__ballot(ck[j] >= candk));
                if (total >= (unsigned)KOUT) {
                    prefix = candk;
                    if (total == (unsigned)KOUT) break;   // wave-uniform
                }
            }
        }

        // T = min{candidate >= prefix} = exact 512th-largest key
        unsigned tmin = 0xFFFFFFFFu;
#pragma unroll
        for (int j = 0; j < 16; ++j) {
            unsigned t = (ck[j] >= prefix) ? ck[j] : 0xFFFFFFFFu;
            tmin = t < tmin ? t : tmin;
        }
#pragma unroll
        for (int off = 32; off; off >>= 1) {
            unsigned o = __shfl_xor(tmin, off, 64);
            tmin = o < tmin ? o : tmin;
        }
        T = tmin;

        // ---- select key > T from the candidate set (superset of >T keys) ---
#pragma unroll
        for (int j = 0; j < 16; ++j) {
            bool p = ck[j] > T;
            unsigned long long m = __ballot(p);
            if (p) sel[wid][mtot + lt_popc(m)] = ck[j];
            mtot += (unsigned)__popcll(m);   // mtot <= 511 by definition of T
        }
    } else {
        // ---- pathological massive-ties fallback (never taken on this data):
        // search exhausted with cnt > CAP  =>  T = prefix exactly, and
        // count(key > prefix) < 512. Select straight from registers.
        T = prefix;
#pragma unroll
        for (int i = 0; i < 64; ++i) {
            bool p = key[i] > T;
            unsigned long long m = __ballot(p);
            if (p) sel[wid][mtot + lt_popc(m)] = key[i];
            mtot += (unsigned)__popcll(m);
        }
    }

    wave_lds_fence();   // order this wave's sel writes before readback

    // ---------------- read back 8/lane, pad ties with T ---------------------
    unsigned x[8];
#pragma unroll
    for (int r = 0; r < 8; ++r) {
        unsigned idx = 8 * (unsigned)lane + r;
        unsigned v = sel[wid][idx];
        x[r] = (idx < mtot) ? v : T;
    }

    // ---------------- bitonic sort 512 descending, wave-private -------------
    // element index e = 8*lane + r; elem keeps max iff ((e&kk)==0)==((e&j)==0)
#pragma unroll
    for (int kk = 2; kk <= 512; kk <<= 1) {
        // cross-lane stages: j = kk/2 .. 8  (lane xor mask = j/8)
#pragma unroll
        for (int j = kk >> 1; j >= 8; j >>= 1) {
            bool km = ((((8 * lane) & kk) == 0) == (((8 * lane) & j) == 0));
#pragma unroll
            for (int r = 0; r < 8; ++r) {
                unsigned p  = __shfl_xor(x[r], j >> 3, 64);
                unsigned mx = x[r] > p ? x[r] : p;
                unsigned mn = x[r] > p ? p : x[r];
                x[r] = km ? mx : mn;
            }
        }
        // in-register stages: j = min(kk/2,4) .. 1
#pragma unroll
        for (int j = (kk >> 1) < 4 ? (kk >> 1) : 4; j >= 1; j >>= 1) {
#pragma unroll
            for (int r = 0; r < 8; ++r) {
                if ((r & j) == 0) {
                    int rp = r | j;
                    unsigned a = x[r], b = x[rp];
                    bool d = (((8 * lane + r) & kk) == 0);
                    unsigned hi = a > b ? a : b;
                    unsigned lo = a > b ? b : a;
                    x[r]  = d ? hi : lo;
                    x[rp] = d ? lo : hi;
                }
            }
        }
    }

    // ---------------- store: 8 consecutive floats per lane ------------------
    float4* dst = (float4*)(out_topk + (size_t)row * KOUT);
    dst[2 * lane + 0] = make_float4(key2f(x[0]), key2f(x[1]), key2f(x[2]), key2f(x[3]));
    dst[2 * lane + 1] = make_float4(key2f(x[4]), key2f(x[5]), key2f(x[6]), key2f(x[7]));
}

extern "C" void kernel_launch(void* const* d_in, const int* in_sizes, int n_in,
                              void* d_out, int out_size, void* d_ws, size_t ws_size,
                              hipStream_t stream) {
    const float* Q      = (const float*)d_in[0];
    const float* scores = (const float*)d_in[1];
    const float* W      = (const float*)d_in[2];
    const float* b      = (const float*)d_in[3];
    float* out_topk = (float*)d_out;                        // [16384, 512]
    float* out_k    = (float*)d_out + (size_t)NROWS * KOUT; // [16384]

    fused_kernel<<<NROWS / 4, 256, 0, stream>>>(scores, Q, W, b, out_topk, out_k);
}

// Round 2
// 425.706 us; speedup vs baseline: 1.1687x; 1.0737x over previous
//
#include <hip/hip_runtime.h>

// Problem constants (B=4, S=4096, D=1024, BASE_K=256, MAX_K=512)
#define SDIM 4096
#define DDIM 1024
#define NROWS 16384
#define KOUT 512
#define CAP 768   // candidate slots per wave. For N(0,1) rows count(key>=T0)=650±23,
                  // so [KOUT, CAP] is a >5-sigma window; anything else -> cold fallback.

// f2key(1.0f): scores ~ N(0,1); P(x >= 1.0) = 0.1587 -> E[count] = 650 of 4096.
// Pure speed hint: wrong-count rows fall back to the exact wide search.
#define T0GUESS 0xBF800000u

__device__ __forceinline__ unsigned f2key(float f) {
    unsigned u = __float_as_uint(f);
    // monotonic bijection: larger key <=> larger float
    return (u & 0x80000000u) ? ~u : (u | 0x80000000u);
}
__device__ __forceinline__ float key2f(unsigned k) {
    unsigned u = (k & 0x80000000u) ? (k ^ 0x80000000u) : ~k;
    return __uint_as_float(u);
}
// popcount of mask restricted to lanes below mine
__device__ __forceinline__ unsigned lt_popc(unsigned long long m) {
    return __builtin_amdgcn_mbcnt_hi((unsigned)(m >> 32),
           __builtin_amdgcn_mbcnt_lo((unsigned)(m & 0xFFFFFFFFull), 0u));
}
// Per-wave LDS ordering: drain this wave's outstanding DS ops.
// Replaces __syncthreads(): every LDS region is a wave-private slice, so
// block-wide coupling of the 4 (imbalanced) waves is pure stall.
__device__ __forceinline__ void wave_lds_fence() {
    asm volatile("s_waitcnt lgkmcnt(0)" ::: "memory");
}

// One WAVE per row (4 rows per 256-thread block).
// __launch_bounds__(256, 1): VGPR cap 512 so key[64] stays RESIDENT in
// registers (default cap of 80 would spill it to scratch -> latency-bound).
__global__ __launch_bounds__(256, 1) void fused_kernel(
    const float* __restrict__ scores, const float* __restrict__ Q,
    const float* __restrict__ W, const float* __restrict__ bias,
    float* __restrict__ out_topk, float* __restrict__ out_k) {

    // 12 KB: candidate buffer per wave; the final >T survivor list ("sel")
    // overlays slots [0..511] once ck[] is register-resident.
    __shared__ unsigned cbuf[4][CAP];

    const int tid  = threadIdx.x;
    const int lane = tid & 63;
    const int wid  = tid >> 6;
    const int row  = blockIdx.x * 4 + wid;

    // ---------------- gate ----------------
    {
        const float4* q4 = (const float4*)(Q + (size_t)row * DDIM);
        const float4* w4 = (const float4*)W;
        float g = 0.f;
#pragma unroll
        for (int i = 0; i < 4; ++i) {
            float4 a = q4[lane + 64 * i];
            float4 b = w4[lane + 64 * i];
            g += a.x * b.x + a.y * b.y + a.z * b.z + a.w * b.w;
        }
#pragma unroll
        for (int off = 32; off; off >>= 1) g += __shfl_down(g, off, 64);
        if (lane == 0) {
            float x   = g + bias[0];
            float imp = 1.0f / (1.0f + expf(-x));
            out_k[row] = (float)(int)(256.0f + 256.0f * imp);
        }
    }

    // ---------------- load 64 keys/lane into registers ----------------
    unsigned key[64];
    {
        const float4* src = (const float4*)(scores + (size_t)row * SDIM);
#pragma unroll
        for (int i = 0; i < 16; ++i) {
            float4 v = src[lane + 64 * i];
            key[4 * i + 0] = f2key(v.x);
            key[4 * i + 1] = f2key(v.y);
            key[4 * i + 2] = f2key(v.z);
            key[4 * i + 3] = f2key(v.w);
        }
    }

    // -------- fast path: fused verify+compact against fixed T0 (ONE pass) ---
    // Replaces the ~10-round wide bitwise search (10x64 serial ballots) with
    // a single 64-ballot pass. Writes are bounds-guarded so an off-guess
    // cannot corrupt the neighbor wave; the fallback then recomputes exactly.
    unsigned cnt = 0;
    {
#pragma unroll
        for (int i = 0; i < 64; ++i) {
            bool p = key[i] >= T0GUESS;
            unsigned long long m = __ballot(p);
            unsigned a = cnt + lt_popc(m);
            if (p && a < CAP) cbuf[wid][a] = key[i];
            cnt += (unsigned)__popcll(m);
        }
    }

    unsigned T;
    unsigned mtot = 0;
    bool have = (cnt >= (unsigned)KOUT) && (cnt <= (unsigned)CAP);

    if (!have) {
        // ---- COLD fallback (not taken for N(0,1) rows): exact wide search --
        // invariant: count(key >= prefix) >= 512 at all times.
        unsigned prefix = 0;
        unsigned tot    = SDIM;
        bool     trig   = false;
#pragma unroll 1
        for (int b = 31; b >= 0; --b) {
            const unsigned candk = prefix | (1u << b);
            unsigned total = 0;
#pragma unroll
            for (int i = 0; i < 64; ++i)
                total += (unsigned)__popcll(__ballot(key[i] >= candk));
            if (total >= (unsigned)KOUT) {   // wave-uniform
                prefix = candk;
                tot    = total;
                if (total <= (unsigned)CAP) { trig = true; break; }
            }
        }
        if (trig) {
            cnt  = tot;
            have = true;
            unsigned c = 0;
#pragma unroll
            for (int i = 0; i < 64; ++i) {
                bool p = key[i] >= prefix;
                unsigned long long m = __ballot(p);
                unsigned a = c + lt_popc(m);
                if (p && a < CAP) cbuf[wid][a] = key[i];
                c += (unsigned)__popcll(m);
            }
        } else {
            // search exhausted with count > CAP => massive ties at T = prefix
            // exactly, and count(key > prefix) < 512. Select straight from regs.
            T = prefix;
#pragma unroll
            for (int i = 0; i < 64; ++i) {
                bool p = key[i] > T;
                unsigned long long m = __ballot(p);
                if (p) cbuf[wid][mtot + lt_popc(m)] = key[i];
                mtot += (unsigned)__popcll(m);
            }
        }
    }

    if (have) {
        wave_lds_fence();   // order compact writes before readback

        // 12 candidates/lane; tail slots masked to 0 (0 can never be >= any
        // candk since candk has a bit set, and never > T).
        unsigned ck[12];
#pragma unroll
        for (int j = 0; j < 12; ++j) {
            unsigned idx = (unsigned)lane + 64u * (unsigned)j;
            unsigned v = cbuf[wid][idx];
            ck[j] = (idx < cnt) ? v : 0u;
        }

        // ---- exact threshold: fresh bitwise search on the candidate set ----
        // (T0 is a lower bound, not a greedy prefix, so restart from bit 31.)
        unsigned pfx = 0;
        if (cnt > (unsigned)KOUT) {
#pragma unroll 1
            for (int b = 31; b >= 0; --b) {
                const unsigned candk = pfx | (1u << b);
                unsigned total = 0;
#pragma unroll
                for (int j = 0; j < 12; ++j)
                    total += (unsigned)__popcll(__ballot(ck[j] >= candk));
                if (total >= (unsigned)KOUT) {
                    pfx = candk;
                    if (total == (unsigned)KOUT) break;   // wave-uniform
                }
            }
        }
        // T = min{candidate >= pfx} = exact 512th-largest key overall.
        // (cnt==512 edge: pfx stays 0, tmin -> 0 via pads, select-all below.)
        unsigned tmin = 0xFFFFFFFFu;
#pragma unroll
        for (int j = 0; j < 12; ++j) {
            unsigned t = (ck[j] >= pfx) ? ck[j] : 0xFFFFFFFFu;
            tmin = t < tmin ? t : tmin;
        }
#pragma unroll
        for (int off = 32; off; off >>= 1) {
            unsigned o = __shfl_xor(tmin, off, 64);
            tmin = o < tmin ? o : tmin;
        }
        T = tmin;

        // ---- select ck > T into cbuf[wid][0..] (overlay; ck is in regs) ----
#pragma unroll
        for (int j = 0; j < 12; ++j) {
            bool p = ck[j] > T;
            unsigned long long m = __ballot(p);
            if (p) cbuf[wid][mtot + lt_popc(m)] = ck[j];
            mtot += (unsigned)__popcll(m);   // <= 512
        }
    }

    wave_lds_fence();   // order survivor writes before readback

    // ---------------- read back 8/lane, pad ties with T ---------------------
    unsigned x[8];
#pragma unroll
    for (int r = 0; r < 8; ++r) {
        unsigned idx = 8 * (unsigned)lane + r;
        unsigned v = cbuf[wid][idx];
        x[r] = (idx < mtot) ? v : T;
    }

    // ---------------- bitonic sort 512 descending, wave-private -------------
    // element index e = 8*lane + r; elem keeps max iff ((e&kk)==0)==((e&j)==0)
#pragma unroll
    for (int kk = 2; kk <= 512; kk <<= 1) {
        // cross-lane stages: j = kk/2 .. 8  (lane xor mask = j/8)
#pragma unroll
        for (int j = kk >> 1; j >= 8; j >>= 1) {
            bool km = ((((8 * lane) & kk) == 0) == (((8 * lane) & j) == 0));
#pragma unroll
            for (int r = 0; r < 8; ++r) {
                unsigned p  = __shfl_xor(x[r], j >> 3, 64);
                unsigned mx = x[r] > p ? x[r] : p;
                unsigned mn = x[r] > p ? p : x[r];
                x[r] = km ? mx : mn;
            }
        }
        // in-register stages: j = min(kk/2,4) .. 1
#pragma unroll
        for (int j = (kk >> 1) < 4 ? (kk >> 1) : 4; j >= 1; j >>= 1) {
#pragma unroll
            for (int r = 0; r < 8; ++r) {
                if ((r & j) == 0) {
                    int rp = r | j;
                    unsigned a = x[r], b = x[rp];
                    bool d = (((8 * lane + r) & kk) == 0);
                    unsigned hi = a > b ? a : b;
                    unsigned lo = a > b ? b : a;
                    x[r]  = d ? hi : lo;
                    x[rp] = d ? lo : hi;
                }
            }
        }
    }

    // ---------------- store: 8 consecutive floats per lane ------------------
    float4* dst = (float4*)(out_topk + (size_t)row * KOUT);
    dst[2 * lane + 0] = make_float4(key2f(x[0]), key2f(x[1]), key2f(x[2]), key2f(x[3]));
    dst[2 * lane + 1] = make_float4(key2f(x[4]), key2f(x[5]), key2f(x[6]), key2f(x[7]));
}

extern "C" void kernel_launch(void* const* d_in, const int* in_sizes, int n_in,
                              void* d_out, int out_size, void* d_ws, size_t ws_size,
                              hipStream_t stream) {
    const float* Q      = (const float*)d_in[0];
    const float* scores = (const float*)d_in[1];
    const float* W      = (const float*)d_in[2];
    const float* b      = (const float*)d_in[3];
    float* out_topk = (float*)d_out;                        // [16384, 512]
    float* out_k    = (float*)d_out + (size_t)NROWS * KOUT; // [16384]

    fused_kernel<<<NROWS / 4, 256, 0, stream>>>(scores, Q, W, b, out_topk, out_k);
}